// Round 1
// baseline (909.247 us; speedup 1.0000x reference)
//
#include <hip/hip_runtime.h>

#define NC    1000000
#define NPAR  100000
#define DIM   64
#define H     4
#define RPE   9
#define SCALE 0.35355339059327373f  // DQK^-0.5
#define CB    128                   // children per fused block

typedef __attribute__((ext_vector_type(8))) short short8;   // 8 bf16 (4 VGPRs)
typedef __attribute__((ext_vector_type(4))) float f32x4;    // MFMA C/D frag

__device__ inline unsigned short f2bf(float f) {
    unsigned int u = __float_as_uint(f);
    u += 0x7fff + ((u >> 16) & 1);          // round-to-nearest-even
    return (unsigned short)(u >> 16);
}
__device__ inline unsigned int pack2bf(float a, float b) {
    return (unsigned int)f2bf(a) | ((unsigned int)f2bf(b) << 16);
}

// ---------------------------------------------------------------------------
// Kernel A: qp[p][o] = SCALE*(x_parent[p].wq[:,o] + bq[o]). Thread per parent.
// ---------------------------------------------------------------------------
__global__ __launch_bounds__(256) void qproj_kernel(const float* __restrict__ xp,
                             const float* __restrict__ wq,
                             const float* __restrict__ bq,
                             float* __restrict__ qp) {
    __shared__ float wqT[32 * 64];   // wqT[o*64+j] = wq[j*32+o]
    __shared__ float bqL[32];
    int tid = threadIdx.x;
    for (int i = tid; i < 2048; i += 256) { int o = i >> 6, j = i & 63; wqT[i] = wq[j * 32 + o]; }
    if (tid < 32) bqL[tid] = bq[tid];
    __syncthreads();
    int p = blockIdx.x * 256 + tid;
    if (p >= NPAR) return;
    float4 x4[16];
    const float4* xr = (const float4*)(xp + (size_t)p * 64);
#pragma unroll
    for (int i = 0; i < 16; ++i) x4[i] = xr[i];
    float* qpr = qp + (size_t)p * 32;
#pragma unroll 1
    for (int o = 0; o < 32; ++o) {
        float acc = bqL[o];
        const float4* w4 = (const float4*)(wqT + o * 64);
#pragma unroll
        for (int j = 0; j < 16; ++j) { float4 w = w4[j], xx = x4[j];
            acc += xx.x * w.x + xx.y * w.y + xx.z * w.z + xx.w * w.w; }
        qpr[o] = acc * SCALE;
    }
}

// ---------------------------------------------------------------------------
// Kernel P: pre-pack B (96x128 bf16 GEMM operand) into global, once.
//  cols 0..31 = k-proj (x,rpe,bias), 32..95 = v-proj, 96..127 = q-rpe.
//  kb 10,11 (k 80..95) are zero padding (kept so fused can load them safely).
// ---------------------------------------------------------------------------
__global__ __launch_bounds__(256) void prepB_kernel(
    const float* __restrict__ wkv, const float* __restrict__ bkv,
    const float* __restrict__ wkr, const float* __restrict__ bkr,
    const float* __restrict__ wqr, const float* __restrict__ bqr,
    uint4* __restrict__ Bg) {
    int tid = threadIdx.x;
    for (int i = tid; i < 12 * 128; i += 256) {
        int kb = i >> 7, n = i & 127;
        float w[8];
#pragma unroll
        for (int jj = 0; jj < 8; ++jj) {
            int k = kb * 8 + jj;
            float val = 0.f;
            if (n < 32) {                       // k-projection (x + rpe + bias)
                if (k < 64)       val = wkv[k * 96 + n];
                else if (k < 73)  val = wkr[(k - 64) * 32 + n];
                else if (k == 73) val = bkv[n] + bkr[n];
            } else if (n < 96) {                // v-projection
                int d = n - 32;
                if (k < 64)       val = wkv[k * 96 + 32 + d];
                else if (k == 73) val = bkv[32 + d];
            } else {                            // q rpe (+bias)
                int o = n - 96;
                if (k >= 64 && k < 73) val = wqr[(k - 64) * 32 + o];
                else if (k == 73)      val = bqr[o];
            }
            w[jj] = val;
        }
        uint4 v;
        v.x = pack2bf(w[0], w[1]); v.y = pack2bf(w[2], w[3]);
        v.z = pack2bf(w[4], w[5]); v.w = pack2bf(w[6], w[7]);
        Bg[kb * 128 + n] = v;
    }
}

// ---------------------------------------------------------------------------
// Kernel B1: per-parent child histogram (1M int atomics, no rank array).
// ---------------------------------------------------------------------------
__global__ __launch_bounds__(256) void hist_kernel(const int* __restrict__ index,
                            int* __restrict__ cnt) {
    int c = blockIdx.x * 256 + threadIdx.x;
    if (c >= NC) return;
    atomicAdd(&cnt[index[c]], 1);
}

// ---------------------------------------------------------------------------
// Kernel B2: single-block exclusive scan cnt[NPAR] -> rowStart[NPAR+1] (+cursor copy).
// ---------------------------------------------------------------------------
__global__ __launch_bounds__(1024) void scan_kernel(const int* __restrict__ cnt,
                            int* __restrict__ rowStart, int* __restrict__ cursor) {
    __shared__ int sums[1024];
    const int CH = (NPAR + 1023) / 1024;   // 98
    int t = threadIdx.x;
    int base = t * CH;
    int local = 0;
    for (int i = 0; i < CH; ++i) { int idx = base + i; if (idx < NPAR) local += cnt[idx]; }
    sums[t] = local;
    __syncthreads();
    for (int off = 1; off < 1024; off <<= 1) {
        int v = sums[t];
        int add = (t >= off) ? sums[t - off] : 0;
        __syncthreads();
        sums[t] = v + add;
        __syncthreads();
    }
    int run = (t > 0) ? sums[t - 1] : 0;
    for (int i = 0; i < CH; ++i) {
        int idx = base + i;
        if (idx < NPAR) { rowStart[idx] = run; cursor[idx] = run; run += cnt[idx]; }
    }
    if (t == 1023) rowStart[NPAR] = run;
}

// ---------------------------------------------------------------------------
// Kernel B3: scatter via cursor atomics: order[cursor[p]++] = c
//  (within-parent order is arbitrary; segment sums are order-independent)
// ---------------------------------------------------------------------------
__global__ __launch_bounds__(256) void scatter_kernel(const int* __restrict__ index,
                               int* __restrict__ cursor,
                               int* __restrict__ order) {
    int c = blockIdx.x * 256 + threadIdx.x;
    if (c >= NC) return;
    order[atomicAdd(&cursor[index[c]], 1)] = c;
}

// ---------------------------------------------------------------------------
// Kernel C: MFMA fused pass. Block = 256 threads / 128 sorted children.
//  LDS ~37.9KB -> 4 blocks/CU (was 80KB -> 2 blocks/CU): latency hiding.
//  GEMM: A(128x80 bf16)=[x|ea|1] x B(96x128 bf16, from global)=[k|v|qrpe].
//  kb 10,11 of A are zero register fragments (no LDS).
// ---------------------------------------------------------------------------
__global__ __launch_bounds__(256, 4) void fused_kernel(
    const float* __restrict__ xc, const float* __restrict__ ea_g,
    const int* __restrict__ index, const int* __restrict__ order,
    const int* __restrict__ rowStart,
    const uint4* __restrict__ Bg,
    const float* __restrict__ qp,
    float* __restrict__ outw, float* __restrict__ sW)
{
    __shared__ __align__(16) char R1[34816];   // A(20K) -> kqT(33792) -> wvS(34816)
    __shared__ float e_lds[CB * 4];
    __shared__ int par_s[CB];
    __shared__ int wcnt[4];
    __shared__ int segStart[130];              // [<=128]=starts+cap, [129]=nseg

    uint4* A4 = (uint4*)R1;                    // A4[kb*128 + c], kb=0..9 (k-chunk of 8)
    float* kqT = (float*)R1;                   // [64][132]: rows 0..31=k, 32..63=qrpe
    float* wvS = (float*)R1;                   // [128][68]: e-scaled v per child

    const int tid  = threadIdx.x;
    const int lane = tid & 63, wave = tid >> 6;
    const int col  = lane & 15, quad = lane >> 4;
    const int G    = blockIdx.x * CB;
    const int validCB = min(NC - G, CB);

    // ---- P1: stage A (two threads per child row; halves in separate waves) ----
    {
        const int half = tid >> 7;             // waves 0,1 = half0; waves 2,3 = half1
        const int c = tid & 127;
        const bool valid = c < validCB;
        int ch = 0, p = 0x7fffffff;
        if (valid) { ch = order[G + c]; p = index[ch]; }
        if (half == 0) {
            par_s[c] = p;
            float4 x4[10];
            if (valid) {
                const float4* xr = (const float4*)(xc + (size_t)ch * 64);
#pragma unroll
                for (int i = 0; i < 10; ++i) x4[i] = xr[i];
            } else {
#pragma unroll
                for (int i = 0; i < 10; ++i) x4[i] = make_float4(0.f, 0.f, 0.f, 0.f);
            }
#pragma unroll
            for (int kb = 0; kb < 5; ++kb) {
                uint4 v;
                v.x = pack2bf(x4[kb * 2].x, x4[kb * 2].y);
                v.y = pack2bf(x4[kb * 2].z, x4[kb * 2].w);
                v.z = pack2bf(x4[kb * 2 + 1].x, x4[kb * 2 + 1].y);
                v.w = pack2bf(x4[kb * 2 + 1].z, x4[kb * 2 + 1].w);
                A4[kb * 128 + c] = v;
            }
        } else {
            float4 x4[6];
            float ear[9];
            if (valid) {
                const float4* xr = (const float4*)(xc + (size_t)ch * 64);
#pragma unroll
                for (int i = 0; i < 6; ++i) x4[i] = xr[10 + i];
                const float* er = ea_g + (size_t)ch * 9;
#pragma unroll
                for (int r = 0; r < 9; ++r) ear[r] = er[r];
            } else {
#pragma unroll
                for (int i = 0; i < 6; ++i) x4[i] = make_float4(0.f, 0.f, 0.f, 0.f);
#pragma unroll
                for (int r = 0; r < 9; ++r) ear[r] = 0.f;
            }
#pragma unroll
            for (int kb = 0; kb < 3; ++kb) {
                uint4 v;
                v.x = pack2bf(x4[kb * 2].x, x4[kb * 2].y);
                v.y = pack2bf(x4[kb * 2].z, x4[kb * 2].w);
                v.z = pack2bf(x4[kb * 2 + 1].x, x4[kb * 2 + 1].y);
                v.w = pack2bf(x4[kb * 2 + 1].z, x4[kb * 2 + 1].w);
                A4[(5 + kb) * 128 + c] = v;
            }
            {
                uint4 v;
                v.x = pack2bf(ear[0], ear[1]); v.y = pack2bf(ear[2], ear[3]);
                v.z = pack2bf(ear[4], ear[5]); v.w = pack2bf(ear[6], ear[7]);
                A4[8 * 128 + c] = v;
            }
            {
                uint4 v;
                v.x = pack2bf(ear[8], valid ? 1.f : 0.f);   // bias row k=73
                v.y = 0u; v.z = 0u; v.w = 0u;
                A4[9 * 128 + c] = v;
            }
        }
    }
    __syncthreads();

    // ---- P2: MFMA. Wave computes 32 children x 128 outputs ----
    f32x4 acc[2][8];
#pragma unroll
    for (int mt = 0; mt < 2; ++mt)
#pragma unroll
        for (int nt = 0; nt < 8; ++nt) acc[mt][nt] = (f32x4){0.f, 0.f, 0.f, 0.f};
    const int wbase = wave * 32;
    const short8* As = (const short8*)A4;
    const short8* Bs = (const short8*)Bg;
    const short8 zero8 = {0, 0, 0, 0, 0, 0, 0, 0};
#pragma unroll 1
    for (int ks = 0; ks < 3; ++ks) {
        const int kb = ks * 4 + quad;
        short8 af0 = zero8, af1 = zero8;
        if (kb < 10) {
            af0 = As[kb * 128 + wbase + col];
            af1 = As[kb * 128 + wbase + 16 + col];
        }
        short8 bf[8];
#pragma unroll
        for (int nt = 0; nt < 6; ++nt) bf[nt] = Bs[kb * 128 + nt * 16 + col];
#pragma unroll
        for (int nt = 0; nt < 6; ++nt) {
            acc[0][nt] = __builtin_amdgcn_mfma_f32_16x16x32_bf16(af0, bf[nt], acc[0][nt], 0, 0, 0);
            acc[1][nt] = __builtin_amdgcn_mfma_f32_16x16x32_bf16(af1, bf[nt], acc[1][nt], 0, 0, 0);
        }
        if (ks == 2) {                 // q-rpe cols only touch k>=64
#pragma unroll
            for (int nt = 6; nt < 8; ++nt) {
                short8 b2 = Bs[kb * 128 + nt * 16 + col];
                acc[0][nt] = __builtin_amdgcn_mfma_f32_16x16x32_bf16(af0, b2, acc[0][nt], 0, 0, 0);
                acc[1][nt] = __builtin_amdgcn_mfma_f32_16x16x32_bf16(af1, b2, acc[1][nt], 0, 0, 0);
            }
        }
    }
    __syncthreads();   // A dead; R1 reused as kqT

    // ---- P3: dump k (n 0..31) and qrpe (n 96..127) frags -> kqT ----
#pragma unroll
    for (int mt = 0; mt < 2; ++mt) {
        int cb = wbase + mt * 16 + quad * 4;
#pragma unroll
        for (int nt = 0; nt < 2; ++nt) {
            int nl = nt * 16 + col;
            *(f32x4*)(kqT + nl * 132 + cb) = acc[mt][nt];
        }
#pragma unroll
        for (int nt = 6; nt < 8; ++nt) {
            int nl = 32 + (nt - 6) * 16 + col;
            *(f32x4*)(kqT + nl * 132 + cb) = acc[mt][nt];
        }
    }
    __syncthreads();

    // ---- P4: glue (thread = child, c<128): compat -> e; segment-head list ----
    {
        const int c = tid;
        bool valid = c < validCB;
        int p = 0x7fffffff;
        if (valid) p = par_s[c];
        float e0 = 0.f, e1 = 0.f, e2 = 0.f, e3 = 0.f;
        if (valid) {
            const float* qpr = qp + (size_t)p * 32;
            float qv[32];
#pragma unroll
            for (int i = 0; i < 8; ++i) *(float4*)(qv + 4 * i) = ((const float4*)qpr)[i];
            float comp[4] = {0.f, 0.f, 0.f, 0.f};
#pragma unroll
            for (int o = 0; o < 32; ++o) {
                float kk = kqT[o * 132 + c];
                float qq = qv[o] + kqT[(32 + o) * 132 + c];
                comp[o >> 3] += qq * kk;
            }
            e0 = __expf(comp[0]); e1 = __expf(comp[1]);
            e2 = __expf(comp[2]); e3 = __expf(comp[3]);
        }
        if (c < CB) *(float4*)(e_lds + c * 4) = make_float4(e0, e1, e2, e3);

        bool ishead = valid && (c == 0 || par_s[c - 1] != p);
        unsigned long long mask = __ballot(ishead);
        if (lane == 0) wcnt[wave] = __popcll(mask);
        __syncthreads();   // kqT reads done; e_lds/wcnt published
        int base = 0;
#pragma unroll
        for (int w = 0; w < 4; ++w) if (w < wave) base += wcnt[w];
        if (ishead) segStart[base + __popcll(mask & ((1ull << lane) - 1))] = c;
        if (tid == 0) {
            int ns = wcnt[0] + wcnt[1] + wcnt[2] + wcnt[3];
            segStart[ns] = validCB;
            segStart[129] = ns;
        }
    }

    // ---- P5: scale v frags by e -> wvS (overwrites kqT region) ----
#pragma unroll
    for (int mt = 0; mt < 2; ++mt) {
        int cb = wbase + mt * 16 + quad * 4;
#pragma unroll
        for (int nt = 2; nt < 6; ++nt) {
            int d = (nt - 2) * 16 + col;
            int h = nt - 2;
#pragma unroll
            for (int r = 0; r < 4; ++r) {
                float e = e_lds[(cb + r) * 4 + h];
                wvS[(cb + r) * 68 + d] = acc[mt][nt][r] * e;
            }
        }
    }
    __syncthreads();

    // ---- P6: segmented reduce. Wave per segment (lane = dim). ----
    {
        int nseg = segStart[129];
        for (int s = wave; s < nseg; s += 4) {
            int a = segStart[s], b = segStart[s + 1];
            int p = par_s[a];
            int d = lane, h = lane >> 4;
            float vs = 0.f, es = 0.f;
            for (int c2 = a; c2 < b; ++c2) {
                vs += wvS[c2 * 68 + d];
                es += e_lds[c2 * 4 + h];
            }
            bool full = (rowStart[p] == G + a) && (rowStart[p + 1] == G + b);
            if (full) {
                outw[(size_t)p * 64 + d] = vs;
                if ((d & 15) == 0) sW[(size_t)p * 4 + h] = es;
            } else {
                atomicAdd(&outw[(size_t)p * 64 + d], vs);
                if ((d & 15) == 0) atomicAdd(&sW[(size_t)p * 4 + h], es);
            }
        }
    }
}

// ---------------------------------------------------------------------------
// Kernel E: out[p][d] /= (s[p][d/16] + 1e-16)
// ---------------------------------------------------------------------------
__global__ __launch_bounds__(256) void norm_kernel(const float* __restrict__ sW,
                                                   float* __restrict__ out) {
    int t = blockIdx.x * 256 + threadIdx.x;
    if (t >= NPAR * 64) return;
    out[t] = out[t] / (sW[(t >> 6) * 4 + ((t >> 4) & 3)] + 1e-16f);
}

// ---------------------------------------------------------------------------
extern "C" void kernel_launch(void* const* d_in, const int* in_sizes, int n_in,
                              void* d_out, int out_size, void* d_ws, size_t ws_size,
                              hipStream_t stream) {
    const float* xc   = (const float*)d_in[0];
    const float* xp   = (const float*)d_in[1];
    const int*   idx  = (const int*)d_in[2];
    const float* ea   = (const float*)d_in[3];
    const float* wq   = (const float*)d_in[4];
    const float* bq   = (const float*)d_in[5];
    const float* wkv  = (const float*)d_in[6];
    const float* bkv  = (const float*)d_in[7];
    const float* wkr  = (const float*)d_in[8];
    const float* bkr  = (const float*)d_in[9];
    const float* wqr  = (const float*)d_in[10];
    const float* bqr  = (const float*)d_in[11];
    float* out = (float*)d_out;

    char* base = (char*)d_ws;
    size_t off = 0;
    auto alloc = [&](size_t bytes) {
        void* r = base + off;
        off += (bytes + 255) & ~(size_t)255;
        return r;
    };
    float* qp       = (float*)alloc((size_t)NPAR * 32 * sizeof(float));   // 12.8 MB
    int*   cnt      = (int*)  alloc((size_t)NPAR * sizeof(int));
    int*   rowStart = (int*)  alloc(((size_t)NPAR + 1) * sizeof(int));
    int*   cursor   = (int*)  alloc((size_t)NPAR * sizeof(int));
    int*   order    = (int*)  alloc((size_t)NC * sizeof(int));            // 4 MB
    float* sW       = (float*)alloc((size_t)NPAR * 4 * sizeof(float));    // 1.6 MB
    uint4* Bg       = (uint4*)alloc((size_t)12 * 128 * sizeof(uint4));    // 24 KB
    (void)ws_size;

    hipMemsetAsync(cnt, 0, (size_t)NPAR * sizeof(int), stream);
    hipMemsetAsync(sW,  0, (size_t)NPAR * 4 * sizeof(float), stream);
    hipMemsetAsync(out, 0, (size_t)NPAR * 64 * sizeof(float), stream);

    qproj_kernel  <<<(NPAR + 255) / 256, 256, 0, stream>>>(xp, wq, bq, qp);
    prepB_kernel  <<<1,                  256, 0, stream>>>(wkv, bkv, wkr, bkr, wqr, bqr, Bg);
    hist_kernel   <<<(NC + 255) / 256,   256, 0, stream>>>(idx, cnt);
    scan_kernel   <<<1,                 1024, 0, stream>>>(cnt, rowStart, cursor);
    scatter_kernel<<<(NC + 255) / 256,   256, 0, stream>>>(idx, cursor, order);
    fused_kernel  <<<(NC + CB - 1) / CB, 256, 0, stream>>>(xc, ea, idx, order, rowStart,
                                                           Bg, qp, out, sW);
    norm_kernel   <<<(NPAR * 64 + 255) / 256, 256, 0, stream>>>(sW, out);
}

// Round 2
// 660.136 us; speedup vs baseline: 1.3774x; 1.3774x over previous
//
#include <hip/hip_runtime.h>

#define NC    1000000
#define NPAR  100000
#define DIM   64
#define H     4
#define RPE   9
#define SCALE 0.35355339059327373f  // DQK^-0.5
#define CB    128                   // children per fused block
#define NBS   ((NPAR + 1023) / 1024)  // 98 scan blocks

typedef __attribute__((ext_vector_type(8))) short short8;   // 8 bf16 (4 VGPRs)
typedef __attribute__((ext_vector_type(4))) float f32x4;    // MFMA C/D frag

__device__ inline unsigned short f2bf(float f) {
    unsigned int u = __float_as_uint(f);
    u += 0x7fff + ((u >> 16) & 1);          // round-to-nearest-even
    return (unsigned short)(u >> 16);
}
__device__ inline unsigned int pack2bf(float a, float b) {
    return (unsigned int)f2bf(a) | ((unsigned int)f2bf(b) << 16);
}

// ---------------------------------------------------------------------------
// Kernel A: qp[p][o] = SCALE*(x_parent[p].wq[:,o] + bq[o]). Thread per parent.
// ---------------------------------------------------------------------------
__global__ __launch_bounds__(256) void qproj_kernel(const float* __restrict__ xp,
                             const float* __restrict__ wq,
                             const float* __restrict__ bq,
                             float* __restrict__ qp) {
    __shared__ float wqT[32 * 64];   // wqT[o*64+j] = wq[j*32+o]
    __shared__ float bqL[32];
    int tid = threadIdx.x;
    for (int i = tid; i < 2048; i += 256) { int o = i >> 6, j = i & 63; wqT[i] = wq[j * 32 + o]; }
    if (tid < 32) bqL[tid] = bq[tid];
    __syncthreads();
    int p = blockIdx.x * 256 + tid;
    if (p >= NPAR) return;
    float4 x4[16];
    const float4* xr = (const float4*)(xp + (size_t)p * 64);
#pragma unroll
    for (int i = 0; i < 16; ++i) x4[i] = xr[i];
    float* qpr = qp + (size_t)p * 32;
#pragma unroll 1
    for (int o = 0; o < 32; ++o) {
        float acc = bqL[o];
        const float4* w4 = (const float4*)(wqT + o * 64);
#pragma unroll
        for (int j = 0; j < 16; ++j) { float4 w = w4[j], xx = x4[j];
            acc += xx.x * w.x + xx.y * w.y + xx.z * w.z + xx.w * w.w; }
        qpr[o] = acc * SCALE;
    }
}

// ---------------------------------------------------------------------------
// Kernel P: pre-pack B (96x128 bf16 GEMM operand) into global, once.
// ---------------------------------------------------------------------------
__global__ __launch_bounds__(256) void prepB_kernel(
    const float* __restrict__ wkv, const float* __restrict__ bkv,
    const float* __restrict__ wkr, const float* __restrict__ bkr,
    const float* __restrict__ wqr, const float* __restrict__ bqr,
    uint4* __restrict__ Bg) {
    int tid = threadIdx.x;
    for (int i = tid; i < 12 * 128; i += 256) {
        int kb = i >> 7, n = i & 127;
        float w[8];
#pragma unroll
        for (int jj = 0; jj < 8; ++jj) {
            int k = kb * 8 + jj;
            float val = 0.f;
            if (n < 32) {                       // k-projection (x + rpe + bias)
                if (k < 64)       val = wkv[k * 96 + n];
                else if (k < 73)  val = wkr[(k - 64) * 32 + n];
                else if (k == 73) val = bkv[n] + bkr[n];
            } else if (n < 96) {                // v-projection
                int d = n - 32;
                if (k < 64)       val = wkv[k * 96 + 32 + d];
                else if (k == 73) val = bkv[32 + d];
            } else {                            // q rpe (+bias)
                int o = n - 96;
                if (k >= 64 && k < 73) val = wqr[(k - 64) * 32 + o];
                else if (k == 73)      val = bqr[o];
            }
            w[jj] = val;
        }
        uint4 v;
        v.x = pack2bf(w[0], w[1]); v.y = pack2bf(w[2], w[3]);
        v.z = pack2bf(w[4], w[5]); v.w = pack2bf(w[6], w[7]);
        Bg[kb * 128 + n] = v;
    }
}

// ---------------------------------------------------------------------------
// Kernel B1: per-parent child histogram (1M int atomics).
// ---------------------------------------------------------------------------
__global__ __launch_bounds__(256) void hist_kernel(const int* __restrict__ index,
                            int* __restrict__ cnt) {
    int c = blockIdx.x * 256 + threadIdx.x;
    if (c >= NC) return;
    atomicAdd(&cnt[index[c]], 1);
}

// ---------------------------------------------------------------------------
// Scan phase A: per-block sums of cnt (98 blocks x 1024 threads).
// ---------------------------------------------------------------------------
__global__ __launch_bounds__(1024) void scanA_kernel(const int* __restrict__ cnt,
                                                     int* __restrict__ bsum) {
    __shared__ int red[16];
    int i = blockIdx.x * 1024 + threadIdx.x;
    int v = (i < NPAR) ? cnt[i] : 0;
#pragma unroll
    for (int off = 32; off; off >>= 1) v += __shfl_down(v, off, 64);
    if ((threadIdx.x & 63) == 0) red[threadIdx.x >> 6] = v;
    __syncthreads();
    if (threadIdx.x < 16) {
        int s = red[threadIdx.x];
#pragma unroll
        for (int off = 8; off; off >>= 1) s += __shfl_down(s, off, 16);
        if (threadIdx.x == 0) bsum[blockIdx.x] = s;
    }
}

// ---------------------------------------------------------------------------
// Scan phase B: exclusive scan of the 98 block sums (1 tiny block).
// ---------------------------------------------------------------------------
__global__ __launch_bounds__(128) void scanB_kernel(int* __restrict__ bsum) {
    __shared__ int s[128];
    int t = threadIdx.x;
    int v = (t < NBS) ? bsum[t] : 0;
    s[t] = v;
    __syncthreads();
    for (int off = 1; off < 128; off <<= 1) {
        int x = s[t];
        int add = (t >= off) ? s[t - off] : 0;
        __syncthreads();
        s[t] = x + add;
        __syncthreads();
    }
    if (t < NBS) bsum[t] = s[t] - v;    // inclusive -> exclusive
}

// ---------------------------------------------------------------------------
// Scan phase C: block-local exclusive scan + block offset -> rowStart, cursor.
// ---------------------------------------------------------------------------
__global__ __launch_bounds__(1024) void scanC_kernel(const int* __restrict__ cnt,
                                                     const int* __restrict__ bsum,
                                                     int* __restrict__ rowStart,
                                                     int* __restrict__ cursor) {
    __shared__ int s[1024];
    int t = threadIdx.x;
    int i = blockIdx.x * 1024 + t;
    int v = (i < NPAR) ? cnt[i] : 0;
    s[t] = v;
    __syncthreads();
    for (int off = 1; off < 1024; off <<= 1) {
        int x = s[t];
        int add = (t >= off) ? s[t - off] : 0;
        __syncthreads();
        s[t] = x + add;
        __syncthreads();
    }
    int excl = s[t] - v + bsum[blockIdx.x];
    if (i < NPAR) { rowStart[i] = excl; cursor[i] = excl; }
    if (i == NPAR - 1) rowStart[NPAR] = excl + v;
}

// ---------------------------------------------------------------------------
// Kernel B3: scatter via cursor atomics: order[cursor[p]++] = c
// ---------------------------------------------------------------------------
__global__ __launch_bounds__(256) void scatter_kernel(const int* __restrict__ index,
                               int* __restrict__ cursor,
                               int* __restrict__ order) {
    int c = blockIdx.x * 256 + threadIdx.x;
    if (c >= NC) return;
    order[atomicAdd(&cursor[index[c]], 1)] = c;
}

// ---------------------------------------------------------------------------
// Kernel C: MFMA fused pass. Block = 256 threads / 128 sorted children.
// ---------------------------------------------------------------------------
__global__ __launch_bounds__(256, 4) void fused_kernel(
    const float* __restrict__ xc, const float* __restrict__ ea_g,
    const int* __restrict__ index, const int* __restrict__ order,
    const int* __restrict__ rowStart,
    const uint4* __restrict__ Bg,
    const float* __restrict__ qp,
    float* __restrict__ outw, float* __restrict__ sW)
{
    __shared__ __align__(16) char R1[34816];   // A(20K) -> kqT(33792) -> wvS(34816)
    __shared__ float e_lds[CB * 4];
    __shared__ int par_s[CB];
    __shared__ int wcnt[4];
    __shared__ int segStart[130];              // [<=128]=starts+cap, [129]=nseg

    uint4* A4 = (uint4*)R1;                    // A4[kb*128 + c], kb=0..9 (k-chunk of 8)
    float* kqT = (float*)R1;                   // [64][132]: rows 0..31=k, 32..63=qrpe
    float* wvS = (float*)R1;                   // [128][68]: e-scaled v per child

    const int tid  = threadIdx.x;
    const int lane = tid & 63, wave = tid >> 6;
    const int col  = lane & 15, quad = lane >> 4;
    const int G    = blockIdx.x * CB;
    const int validCB = min(NC - G, CB);

    // ---- P1: stage A (two threads per child row; halves in separate waves) ----
    {
        const int half = tid >> 7;             // waves 0,1 = half0; waves 2,3 = half1
        const int c = tid & 127;
        const bool valid = c < validCB;
        int ch = 0, p = 0x7fffffff;
        if (valid) { ch = order[G + c]; p = index[ch]; }
        if (half == 0) {
            par_s[c] = p;
            float4 x4[10];
            if (valid) {
                const float4* xr = (const float4*)(xc + (size_t)ch * 64);
#pragma unroll
                for (int i = 0; i < 10; ++i) x4[i] = xr[i];
            } else {
#pragma unroll
                for (int i = 0; i < 10; ++i) x4[i] = make_float4(0.f, 0.f, 0.f, 0.f);
            }
#pragma unroll
            for (int kb = 0; kb < 5; ++kb) {
                uint4 v;
                v.x = pack2bf(x4[kb * 2].x, x4[kb * 2].y);
                v.y = pack2bf(x4[kb * 2].z, x4[kb * 2].w);
                v.z = pack2bf(x4[kb * 2 + 1].x, x4[kb * 2 + 1].y);
                v.w = pack2bf(x4[kb * 2 + 1].z, x4[kb * 2 + 1].w);
                A4[kb * 128 + c] = v;
            }
        } else {
            float4 x4[6];
            float ear[9];
            if (valid) {
                const float4* xr = (const float4*)(xc + (size_t)ch * 64);
#pragma unroll
                for (int i = 0; i < 6; ++i) x4[i] = xr[10 + i];
                const float* er = ea_g + (size_t)ch * 9;
#pragma unroll
                for (int r = 0; r < 9; ++r) ear[r] = er[r];
            } else {
#pragma unroll
                for (int i = 0; i < 6; ++i) x4[i] = make_float4(0.f, 0.f, 0.f, 0.f);
#pragma unroll
                for (int r = 0; r < 9; ++r) ear[r] = 0.f;
            }
#pragma unroll
            for (int kb = 0; kb < 3; ++kb) {
                uint4 v;
                v.x = pack2bf(x4[kb * 2].x, x4[kb * 2].y);
                v.y = pack2bf(x4[kb * 2].z, x4[kb * 2].w);
                v.z = pack2bf(x4[kb * 2 + 1].x, x4[kb * 2 + 1].y);
                v.w = pack2bf(x4[kb * 2 + 1].z, x4[kb * 2 + 1].w);
                A4[(5 + kb) * 128 + c] = v;
            }
            {
                uint4 v;
                v.x = pack2bf(ear[0], ear[1]); v.y = pack2bf(ear[2], ear[3]);
                v.z = pack2bf(ear[4], ear[5]); v.w = pack2bf(ear[6], ear[7]);
                A4[8 * 128 + c] = v;
            }
            {
                uint4 v;
                v.x = pack2bf(ear[8], valid ? 1.f : 0.f);   // bias row k=73
                v.y = 0u; v.z = 0u; v.w = 0u;
                A4[9 * 128 + c] = v;
            }
        }
    }
    __syncthreads();

    // ---- P2: MFMA. Wave computes 32 children x 128 outputs ----
    f32x4 acc[2][8];
#pragma unroll
    for (int mt = 0; mt < 2; ++mt)
#pragma unroll
        for (int nt = 0; nt < 8; ++nt) acc[mt][nt] = (f32x4){0.f, 0.f, 0.f, 0.f};
    const int wbase = wave * 32;
    const short8* As = (const short8*)A4;
    const short8* Bs = (const short8*)Bg;
    const short8 zero8 = {0, 0, 0, 0, 0, 0, 0, 0};
#pragma unroll 1
    for (int ks = 0; ks < 3; ++ks) {
        const int kb = ks * 4 + quad;
        short8 af0 = zero8, af1 = zero8;
        if (kb < 10) {
            af0 = As[kb * 128 + wbase + col];
            af1 = As[kb * 128 + wbase + 16 + col];
        }
        short8 bf[8];
#pragma unroll
        for (int nt = 0; nt < 6; ++nt) bf[nt] = Bs[kb * 128 + nt * 16 + col];
#pragma unroll
        for (int nt = 0; nt < 6; ++nt) {
            acc[0][nt] = __builtin_amdgcn_mfma_f32_16x16x32_bf16(af0, bf[nt], acc[0][nt], 0, 0, 0);
            acc[1][nt] = __builtin_amdgcn_mfma_f32_16x16x32_bf16(af1, bf[nt], acc[1][nt], 0, 0, 0);
        }
        if (ks == 2) {                 // q-rpe cols only touch k>=64
#pragma unroll
            for (int nt = 6; nt < 8; ++nt) {
                short8 b2 = Bs[kb * 128 + nt * 16 + col];
                acc[0][nt] = __builtin_amdgcn_mfma_f32_16x16x32_bf16(af0, b2, acc[0][nt], 0, 0, 0);
                acc[1][nt] = __builtin_amdgcn_mfma_f32_16x16x32_bf16(af1, b2, acc[1][nt], 0, 0, 0);
            }
        }
    }
    __syncthreads();   // A dead; R1 reused as kqT

    // ---- P3: dump k (n 0..31) and qrpe (n 96..127) frags -> kqT ----
#pragma unroll
    for (int mt = 0; mt < 2; ++mt) {
        int cb = wbase + mt * 16 + quad * 4;
#pragma unroll
        for (int nt = 0; nt < 2; ++nt) {
            int nl = nt * 16 + col;
            *(f32x4*)(kqT + nl * 132 + cb) = acc[mt][nt];
        }
#pragma unroll
        for (int nt = 6; nt < 8; ++nt) {
            int nl = 32 + (nt - 6) * 16 + col;
            *(f32x4*)(kqT + nl * 132 + cb) = acc[mt][nt];
        }
    }
    __syncthreads();

    // ---- P4: glue (thread = child, c<128): compat -> e; segment-head list ----
    {
        const int c = tid;
        bool valid = c < validCB;
        int p = 0x7fffffff;
        if (valid) p = par_s[c];
        float e0 = 0.f, e1 = 0.f, e2 = 0.f, e3 = 0.f;
        if (valid) {
            const float* qpr = qp + (size_t)p * 32;
            float qv[32];
#pragma unroll
            for (int i = 0; i < 8; ++i) *(float4*)(qv + 4 * i) = ((const float4*)qpr)[i];
            float comp[4] = {0.f, 0.f, 0.f, 0.f};
#pragma unroll
            for (int o = 0; o < 32; ++o) {
                float kk = kqT[o * 132 + c];
                float qq = qv[o] + kqT[(32 + o) * 132 + c];
                comp[o >> 3] += qq * kk;
            }
            e0 = __expf(comp[0]); e1 = __expf(comp[1]);
            e2 = __expf(comp[2]); e3 = __expf(comp[3]);
        }
        if (c < CB) *(float4*)(e_lds + c * 4) = make_float4(e0, e1, e2, e3);

        bool ishead = valid && (c == 0 || par_s[c - 1] != p);
        unsigned long long mask = __ballot(ishead);
        if (lane == 0) wcnt[wave] = __popcll(mask);
        __syncthreads();   // kqT reads done; e_lds/wcnt published
        int base = 0;
#pragma unroll
        for (int w = 0; w < 4; ++w) if (w < wave) base += wcnt[w];
        if (ishead) segStart[base + __popcll(mask & ((1ull << lane) - 1))] = c;
        if (tid == 0) {
            int ns = wcnt[0] + wcnt[1] + wcnt[2] + wcnt[3];
            segStart[ns] = validCB;
            segStart[129] = ns;
        }
    }

    // ---- P5: scale v frags by e -> wvS (overwrites kqT region) ----
#pragma unroll
    for (int mt = 0; mt < 2; ++mt) {
        int cb = wbase + mt * 16 + quad * 4;
#pragma unroll
        for (int nt = 2; nt < 6; ++nt) {
            int d = (nt - 2) * 16 + col;
            int h = nt - 2;
#pragma unroll
            for (int r = 0; r < 4; ++r) {
                float e = e_lds[(cb + r) * 4 + h];
                wvS[(cb + r) * 68 + d] = acc[mt][nt][r] * e;
            }
        }
    }
    __syncthreads();

    // ---- P6: segmented reduce. Wave per segment (lane = dim). ----
    {
        int nseg = segStart[129];
        for (int s = wave; s < nseg; s += 4) {
            int a = segStart[s], b = segStart[s + 1];
            int p = par_s[a];
            int d = lane, h = lane >> 4;
            float vs = 0.f, es = 0.f;
            for (int c2 = a; c2 < b; ++c2) {
                vs += wvS[c2 * 68 + d];
                es += e_lds[c2 * 4 + h];
            }
            bool full = (rowStart[p] == G + a) && (rowStart[p + 1] == G + b);
            if (full) {
                outw[(size_t)p * 64 + d] = vs;
                if ((d & 15) == 0) sW[(size_t)p * 4 + h] = es;
            } else {
                atomicAdd(&outw[(size_t)p * 64 + d], vs);
                if ((d & 15) == 0) atomicAdd(&sW[(size_t)p * 4 + h], es);
            }
        }
    }
}

// ---------------------------------------------------------------------------
// Kernel E: out[p][d] /= (s[p][d/16] + 1e-16)
// ---------------------------------------------------------------------------
__global__ __launch_bounds__(256) void norm_kernel(const float* __restrict__ sW,
                                                   float* __restrict__ out) {
    int t = blockIdx.x * 256 + threadIdx.x;
    if (t >= NPAR * 64) return;
    out[t] = out[t] / (sW[(t >> 6) * 4 + ((t >> 4) & 3)] + 1e-16f);
}

// ---------------------------------------------------------------------------
extern "C" void kernel_launch(void* const* d_in, const int* in_sizes, int n_in,
                              void* d_out, int out_size, void* d_ws, size_t ws_size,
                              hipStream_t stream) {
    const float* xc   = (const float*)d_in[0];
    const float* xp   = (const float*)d_in[1];
    const int*   idx  = (const int*)d_in[2];
    const float* ea   = (const float*)d_in[3];
    const float* wq   = (const float*)d_in[4];
    const float* bq   = (const float*)d_in[5];
    const float* wkv  = (const float*)d_in[6];
    const float* bkv  = (const float*)d_in[7];
    const float* wkr  = (const float*)d_in[8];
    const float* bkr  = (const float*)d_in[9];
    const float* wqr  = (const float*)d_in[10];
    const float* bqr  = (const float*)d_in[11];
    float* out = (float*)d_out;

    char* base = (char*)d_ws;
    size_t off = 0;
    auto alloc = [&](size_t bytes) {
        void* r = base + off;
        off += (bytes + 255) & ~(size_t)255;
        return r;
    };
    float* qp       = (float*)alloc((size_t)NPAR * 32 * sizeof(float));   // 12.8 MB
    int*   cnt      = (int*)  alloc((size_t)NPAR * sizeof(int));
    int*   rowStart = (int*)  alloc(((size_t)NPAR + 1) * sizeof(int));
    int*   cursor   = (int*)  alloc((size_t)NPAR * sizeof(int));
    int*   order    = (int*)  alloc((size_t)NC * sizeof(int));            // 4 MB
    float* sW       = (float*)alloc((size_t)NPAR * 4 * sizeof(float));    // 1.6 MB
    int*   bsum     = (int*)  alloc((size_t)NBS * sizeof(int));
    uint4* Bg       = (uint4*)alloc((size_t)12 * 128 * sizeof(uint4));    // 24 KB
    (void)ws_size;

    hipMemsetAsync(cnt, 0, (size_t)NPAR * sizeof(int), stream);
    hipMemsetAsync(sW,  0, (size_t)NPAR * 4 * sizeof(float), stream);
    hipMemsetAsync(out, 0, (size_t)NPAR * 64 * sizeof(float), stream);

    qproj_kernel  <<<(NPAR + 255) / 256, 256, 0, stream>>>(xp, wq, bq, qp);
    prepB_kernel  <<<1,                  256, 0, stream>>>(wkv, bkv, wkr, bkr, wqr, bqr, Bg);
    hist_kernel   <<<(NC + 255) / 256,   256, 0, stream>>>(idx, cnt);
    scanA_kernel  <<<NBS,               1024, 0, stream>>>(cnt, bsum);
    scanB_kernel  <<<1,                  128, 0, stream>>>(bsum);
    scanC_kernel  <<<NBS,               1024, 0, stream>>>(cnt, bsum, rowStart, cursor);
    scatter_kernel<<<(NC + 255) / 256,   256, 0, stream>>>(idx, cursor, order);
    fused_kernel  <<<(NC + CB - 1) / CB, 256, 0, stream>>>(xc, ea, idx, order, rowStart,
                                                           Bg, qp, out, sW);
    norm_kernel   <<<(NPAR * 64 + 255) / 256, 256, 0, stream>>>(sW, out);
}